// Round 7
// baseline (166.592 us; speedup 1.0000x reference)
//
#include <hip/hip_runtime.h>

// ---------------------------------------------------------------------------
// GCN 3-layer forward on a static graph.
// R2: transforms -> LDS-tiled register-blocked SGEMM.
// R3: single-block scan -> 3-kernel parallel scan.
// R4: interleaved int2 CSR; aggregate unrolled x4; aggregate2+transform3 fused.
// R5: 8-way replicated global-atomic histograms -- NULL. Finding: device-scope
//     atomics are throughput-bound (~25G/s) regardless of address spread.
// R6: zero global atomics -- LDS histograms + rank-scatter. 199->164us.
// R7: layer-1 gemm retiled 64x128/TN=8 -> 64x64/TN=4 with 2 col-blocks:
//     kills the structural 4-way Ws bank conflict (tcol*8 spans 512B; tcol*4
//     spans 256B = free 2-way) and doubles grid to 1024 blocks (4/CU, was
//     2/CU grid-capped at 17% occupancy).
// ---------------------------------------------------------------------------

#define NB 128     // edge groups == hist/scatter blocks
#define NW4 8192   // N/4 packed words (N = 32768)

typedef unsigned int uint32;

// Per-block src+dst histograms over all N nodes, packed u8 x4 per word.
__global__ __launch_bounds__(1024) void lds_hist_kernel(const int* __restrict__ src,
                                                        const int* __restrict__ dst,
                                                        uint32* __restrict__ part_src,
                                                        uint32* __restrict__ part_dst,
                                                        int e, int epb) {
  __shared__ uint32 hs[NW4];
  __shared__ uint32 hd[NW4];
  const int t = threadIdx.x;
  for (int w = t; w < NW4; w += 1024) {
    hs[w] = 0;
    hd[w] = 0;
  }
  __syncthreads();
  const int base = blockIdx.x * epb;
  for (int k = t; k < epb; k += 1024) {
    int i = base + k;
    if (i < e) {
      int s = src[i], d = dst[i];
      atomicAdd(&hs[s >> 2], 1u << ((s & 3) * 8));
      atomicAdd(&hd[d >> 2], 1u << ((d & 3) * 8));
    }
  }
  __syncthreads();
  uint32* ps = part_src + (size_t)blockIdx.x * NW4;
  uint32* pd = part_dst + (size_t)blockIdx.x * NW4;
  for (int w = t; w < NW4; w += 1024) {
    ps[w] = hs[w];
    pd[w] = hd[w];
  }
}

// Packed u32 adds across the NB partials, unpack -> norms + in_deg.
__global__ void reduce_norm_kernel(const uint32* __restrict__ part_src,
                                   const uint32* __restrict__ part_dst,
                                   float* __restrict__ norm_src, float* __restrict__ norm_dst,
                                   int* __restrict__ in_deg, int n4) {
  int w = blockIdx.x * blockDim.x + threadIdx.x;
  if (w >= n4) return;
  uint32 ss = 0, sd = 0;
  for (int r = 0; r < NB; ++r) {
    ss += part_src[(size_t)r * n4 + w];
    sd += part_dst[(size_t)r * n4 + w];
  }
#pragma unroll
  for (int j = 0; j < 4; ++j) {
    int v = w * 4 + j;
    int od = (ss >> (j * 8)) & 0xff;
    int id = (sd >> (j * 8)) & 0xff;
    norm_src[v] = 1.0f / sqrtf((float)max(od, 1));
    norm_dst[v] = 1.0f / sqrtf((float)max(id, 1));
    in_deg[v] = id;
  }
}

// --- parallel scan over in_deg -> row_ptr -----------------------------------
__global__ __launch_bounds__(256) void scan_partials_a(const int* __restrict__ deg,
                                                       int* __restrict__ block_sums, int n) {
  const int t = threadIdx.x;
  const int gid = blockIdx.x * 256 + t;
  int d = (gid < n) ? deg[gid] : 0;
#pragma unroll
  for (int off = 32; off > 0; off >>= 1) d += __shfl_down(d, off, 64);
  __shared__ int wsum[4];
  if ((t & 63) == 0) wsum[t >> 6] = d;
  __syncthreads();
  if (t == 0) block_sums[blockIdx.x] = wsum[0] + wsum[1] + wsum[2] + wsum[3];
}

__global__ __launch_bounds__(256) void scan_partials_b(int* __restrict__ block_sums,
                                                       int* __restrict__ block_offs, int nb) {
  __shared__ int sh[256];
  const int t = threadIdx.x;
  sh[t] = (t < nb) ? block_sums[t] : 0;
  __syncthreads();
  for (int off = 1; off < 256; off <<= 1) {
    int v = sh[t];
    int add = (t >= off) ? sh[t - off] : 0;
    __syncthreads();
    sh[t] = v + add;
    __syncthreads();
  }
  if (t < nb) block_offs[t] = (t > 0) ? sh[t - 1] : 0; // exclusive
}

__global__ __launch_bounds__(256) void scan_write(const int* __restrict__ deg,
                                                  const int* __restrict__ block_offs,
                                                  int* __restrict__ row_ptr, int n) {
  __shared__ int sh[256];
  const int t = threadIdx.x;
  const int gid = blockIdx.x * 256 + t;
  int d = (gid < n) ? deg[gid] : 0;
  sh[t] = d;
  __syncthreads();
  for (int off = 1; off < 256; off <<= 1) {
    int v = sh[t];
    int add = (t >= off) ? sh[t - off] : 0;
    __syncthreads();
    sh[t] = v + add;
    __syncthreads();
  }
  if (gid < n) {
    int excl = block_offs[blockIdx.x] + sh[t] - d;
    row_ptr[gid] = excl;
    if (gid == n - 1) row_ptr[n] = excl + d;
  }
}

// goff[r][v] = row_ptr[v] + sum_{r'<r} cnt[r'][v]
__global__ void group_offs_kernel(const uint32* __restrict__ part_dst,
                                  const int* __restrict__ row_ptr,
                                  int* __restrict__ goff, int n) {
  int v = blockIdx.x * blockDim.x + threadIdx.x;
  if (v >= n) return;
  int base = row_ptr[v];
  const int w = v >> 2;
  const int sh = (v & 3) * 8;
  const int n4 = n >> 2;
  for (int r = 0; r < NB; ++r) {
    goff[(size_t)r * n + v] = base;
    base += (part_dst[(size_t)r * n4 + w] >> sh) & 0xff;
  }
}

// Scatter with per-block LDS rank histogram -> unique positions, no global atomics.
__global__ __launch_bounds__(1024) void scatter_kernel(const int* __restrict__ src,
                                                       const int* __restrict__ dst,
                                                       const float* __restrict__ ew,
                                                       const int* __restrict__ goff,
                                                       int2* __restrict__ csr,
                                                       int n, int e, int epb) {
  __shared__ uint32 rk[NW4];
  const int t = threadIdx.x;
  for (int w = t; w < NW4; w += 1024) rk[w] = 0;
  __syncthreads();
  const int base = blockIdx.x * epb;
  const int* gof = goff + (size_t)blockIdx.x * n;
  for (int k = t; k < epb; k += 1024) {
    int i = base + k;
    if (i < e) {
      int d = dst[i];
      uint32 sh = (d & 3) * 8;
      uint32 old = atomicAdd(&rk[d >> 2], 1u << sh);
      int rank = (old >> sh) & 0xff;
      csr[gof[d] + rank] = make_int2(src[i], __float_as_int(ew[i]));
    }
  }
}

// ---------------------------------------------------------------------------
// Tiled SGEMM transform: ht = (x * norm_src[:,None]) @ W
// TN=4 keeps the Ws float4 read within a 256B span (free 2-way aliasing);
// BN=64 + col-block grid dim doubles block count for occupancy.
// ---------------------------------------------------------------------------
template <int K, int OUT, int BM, int BN, int TM, int TN, int BK>
__global__ __launch_bounds__(256) void gemm_transform(const float* __restrict__ x,
                                                      const float* __restrict__ W,
                                                      const float* __restrict__ norm_src,
                                                      float* __restrict__ ht, int n) {
  static_assert((BN / TN) * (BM / TM) == 256, "thread grid");
  __shared__ float Xs[BK][BM + 1];
  __shared__ float Ws[BK][BN];

  const int tid = threadIdx.x;
  const int tcol = tid % (BN / TN);
  const int trow = tid / (BN / TN);
  const int row0 = blockIdx.x * BM;
  const int col0 = blockIdx.y * BN;

  float acc[TM][TN];
#pragma unroll
  for (int i = 0; i < TM; ++i)
#pragma unroll
    for (int j = 0; j < TN; ++j) acc[i][j] = 0.f;

  for (int k0 = 0; k0 < K; k0 += BK) {
    constexpr int XL = BM * BK / 4 / 256;
#pragma unroll
    for (int p = 0; p < XL; ++p) {
      int idx = p * 256 + tid;
      int kg = idx % (BK / 4);
      int r = idx / (BK / 4);
      float ns = norm_src[row0 + r];
      float4 v = *reinterpret_cast<const float4*>(x + (size_t)(row0 + r) * K + k0 + kg * 4);
      Xs[kg * 4 + 0][r] = v.x * ns;
      Xs[kg * 4 + 1][r] = v.y * ns;
      Xs[kg * 4 + 2][r] = v.z * ns;
      Xs[kg * 4 + 3][r] = v.w * ns;
    }
    constexpr int WL = BK * BN / 4 / 256;
#pragma unroll
    for (int p = 0; p < WL; ++p) {
      int idx = p * 256 + tid;
      int cg = idx % (BN / 4);
      int kr = idx / (BN / 4);
      float4 v = *reinterpret_cast<const float4*>(W + (size_t)(k0 + kr) * OUT + col0 + cg * 4);
      *reinterpret_cast<float4*>(&Ws[kr][cg * 4]) = v;
    }
    __syncthreads();

#pragma unroll
    for (int k = 0; k < BK; ++k) {
      float a[TM], b[TN];
#pragma unroll
      for (int i = 0; i < TM; ++i) a[i] = Xs[k][trow * TM + i];
#pragma unroll
      for (int j = 0; j < TN; ++j) b[j] = Ws[k][tcol * TN + j];
#pragma unroll
      for (int i = 0; i < TM; ++i)
#pragma unroll
        for (int j = 0; j < TN; ++j) acc[i][j] += a[i] * b[j];
    }
    __syncthreads();
  }

#pragma unroll
  for (int i = 0; i < TM; ++i) {
    int row = row0 + trow * TM + i;
#pragma unroll
    for (int j = 0; j < TN; j += 4) {
      float4 r = {acc[i][j], acc[i][j + 1], acc[i][j + 2], acc[i][j + 3]};
      *reinterpret_cast<float4*>(ht + (size_t)row * OUT + col0 + tcol * TN + j) = r;
    }
  }
}

#define GATHER4(e, acc)                                                             \
  {                                                                                 \
    float w_ = __int_as_float(e.y);                                                 \
    float4 h_ = *reinterpret_cast<const float4*>(ht + (size_t)e.x * OUT + cg * 4);  \
    acc.x += w_ * h_.x;                                                             \
    acc.y += w_ * h_.y;                                                             \
    acc.z += w_ * h_.z;                                                             \
    acc.w += w_ * h_.w;                                                             \
  }

// out[v][col] = tanh( norm_dst[v] * sum_{e in CSR[v]} w_e * ht[src_e][col] + bias[col] )
template <int OUT>
__global__ void aggregate_kernel(const float* __restrict__ ht, const int* __restrict__ row_ptr,
                                 const int2* __restrict__ csr, const float* __restrict__ norm_dst,
                                 const float* __restrict__ bias, float* __restrict__ out, int n) {
  constexpr int LPN = OUT / 4;
  constexpr int NPB = 256 / LPN;
  const int tid = threadIdx.x;
  const int cg = tid % LPN;
  const int v = blockIdx.x * NPB + tid / LPN;
  if (v >= n) return;

  const int s0 = row_ptr[v];
  const int s1 = row_ptr[v + 1];
  float4 a0 = {0, 0, 0, 0}, a1 = {0, 0, 0, 0}, a2 = {0, 0, 0, 0}, a3 = {0, 0, 0, 0};
  int i = s0;
  for (; i + 4 <= s1; i += 4) {
    int2 e0 = csr[i], e1 = csr[i + 1], e2 = csr[i + 2], e3 = csr[i + 3];
    GATHER4(e0, a0);
    GATHER4(e1, a1);
    GATHER4(e2, a2);
    GATHER4(e3, a3);
  }
  for (; i < s1; ++i) {
    int2 e = csr[i];
    GATHER4(e, a0);
  }
  float nd = norm_dst[v];
  float4 b4 = *reinterpret_cast<const float4*>(bias + cg * 4);
  float4 r;
  r.x = tanhf((a0.x + a1.x + a2.x + a3.x) * nd + b4.x);
  r.y = tanhf((a0.y + a1.y + a2.y + a3.y) * nd + b4.y);
  r.z = tanhf((a0.z + a1.z + a2.z + a3.z) * nd + b4.z);
  r.w = tanhf((a0.w + a1.w + a2.w + a3.w) * nd + b4.w);
  *reinterpret_cast<float4*>(out + (size_t)v * OUT + cg * 4) = r;
}

// Layer-2 aggregate fused with layer-3 transform.
__global__ void aggregate2_fuse3(const float* __restrict__ ht, const int* __restrict__ row_ptr,
                                 const int2* __restrict__ csr, const float* __restrict__ norm_dst,
                                 const float* __restrict__ norm_src, const float* __restrict__ bias,
                                 const float* __restrict__ W3, float* __restrict__ ht3, int n) {
  constexpr int OUT = 64;
  constexpr int LPN = OUT / 4; // 16
  constexpr int NPB = 256 / LPN;
  const int tid = threadIdx.x;
  const int cg = tid % LPN;
  const int v = blockIdx.x * NPB + tid / LPN;
  if (v >= n) return;

  const int s0 = row_ptr[v];
  const int s1 = row_ptr[v + 1];
  float4 a0 = {0, 0, 0, 0}, a1 = {0, 0, 0, 0}, a2 = {0, 0, 0, 0}, a3 = {0, 0, 0, 0};
  int i = s0;
  for (; i + 4 <= s1; i += 4) {
    int2 e0 = csr[i], e1 = csr[i + 1], e2 = csr[i + 2], e3 = csr[i + 3];
    GATHER4(e0, a0);
    GATHER4(e1, a1);
    GATHER4(e2, a2);
    GATHER4(e3, a3);
  }
  for (; i < s1; ++i) {
    int2 e = csr[i];
    GATHER4(e, a0);
  }
  float nd = norm_dst[v];
  float4 b4 = *reinterpret_cast<const float4*>(bias + cg * 4);
  float ox = tanhf((a0.x + a1.x + a2.x + a3.x) * nd + b4.x);
  float oy = tanhf((a0.y + a1.y + a2.y + a3.y) * nd + b4.y);
  float oz = tanhf((a0.z + a1.z + a2.z + a3.z) * nd + b4.z);
  float ow = tanhf((a0.w + a1.w + a2.w + a3.w) * nd + b4.w);
  float4 w3 = *reinterpret_cast<const float4*>(W3 + cg * 4);
  float p = ox * w3.x + oy * w3.y + oz * w3.z + ow * w3.w;
#pragma unroll
  for (int m = 1; m < 16; m <<= 1) p += __shfl_xor(p, m, 64);
  if (cg == 0) ht3[v] = p * norm_src[v];
}

// Layer 3 aggregate: out[v] = norm_dst[v] * sum w_e*ht3[src_e] + b3 (no tanh)
__global__ void aggregate3_kernel(const float* __restrict__ ht3, const int* __restrict__ row_ptr,
                                  const int2* __restrict__ csr, const float* __restrict__ norm_dst,
                                  const float* __restrict__ b3, float* __restrict__ out, int n) {
  int v = blockIdx.x * blockDim.x + threadIdx.x;
  if (v >= n) return;
  const int s0 = row_ptr[v];
  const int s1 = row_ptr[v + 1];
  float p0 = 0.f, p1 = 0.f, p2 = 0.f, p3 = 0.f;
  int i = s0;
  for (; i + 4 <= s1; i += 4) {
    int2 e0 = csr[i], e1 = csr[i + 1], e2 = csr[i + 2], e3 = csr[i + 3];
    p0 += __int_as_float(e0.y) * ht3[e0.x];
    p1 += __int_as_float(e1.y) * ht3[e1.x];
    p2 += __int_as_float(e2.y) * ht3[e2.x];
    p3 += __int_as_float(e3.y) * ht3[e3.x];
  }
  for (; i < s1; ++i) {
    int2 e = csr[i];
    p0 += __int_as_float(e.y) * ht3[e.x];
  }
  out[v] = (p0 + p1 + p2 + p3) * norm_dst[v] + b3[0];
}

extern "C" void kernel_launch(void* const* d_in, const int* in_sizes, int n_in,
                              void* d_out, int out_size, void* d_ws, size_t ws_size,
                              hipStream_t stream) {
  const float* b_z = (const float*)d_in[0];
  const int* src = (const int*)d_in[1];
  const int* dst = (const int*)d_in[2];
  const float* ew = (const float*)d_in[3];
  const float* W1 = (const float*)d_in[4];
  const float* b1 = (const float*)d_in[5];
  const float* W2 = (const float*)d_in[6];
  const float* b2 = (const float*)d_in[7];
  const float* W3 = (const float*)d_in[8];
  const float* b3 = (const float*)d_in[9];

  const int N = in_sizes[0] / 256; // 32768
  const int E = in_sizes[1];       // 524288
  const int N4 = N / 4;
  const int epb = (E + NB - 1) / NB; // 4096

  char* ws = (char*)d_ws;
  size_t off = 0;
  auto alloc = [&](size_t bytes) -> void* {
    void* p = ws + off;
    off += (bytes + 255) & ~(size_t)255;
    return p;
  };

  uint32* part_src = (uint32*)alloc((size_t)NB * N4 * 4); // 4 MB
  uint32* part_dst = (uint32*)alloc((size_t)NB * N4 * 4); // 4 MB
  int* goff = (int*)alloc((size_t)NB * N * 4);            // 16 MB
  float* norm_src = (float*)alloc((size_t)N * 4);
  float* norm_dst = (float*)alloc((size_t)N * 4);
  int* in_deg = (int*)alloc((size_t)N * 4);
  int* row_ptr = (int*)alloc((size_t)(N + 1) * 4);
  int* block_sums = (int*)alloc(256 * 4);
  int* block_offs = (int*)alloc(256 * 4);
  int2* csr = (int2*)alloc((size_t)E * 8);
  float* HT = (float*)alloc((size_t)N * 128 * 4);   // ht1 / ht2 (reused)
  float* ACT1 = (float*)alloc((size_t)N * 128 * 4); // layer1 activation
  float* HT3 = (float*)alloc((size_t)N * 4);

  const int nBlocks = (N + 255) / 256; // 128

  lds_hist_kernel<<<NB, 1024, 0, stream>>>(src, dst, part_src, part_dst, E, epb);
  reduce_norm_kernel<<<(N4 + 255) / 256, 256, 0, stream>>>(part_src, part_dst, norm_src,
                                                           norm_dst, in_deg, N4);
  scan_partials_a<<<nBlocks, 256, 0, stream>>>(in_deg, block_sums, N);
  scan_partials_b<<<1, 256, 0, stream>>>(block_sums, block_offs, nBlocks);
  scan_write<<<nBlocks, 256, 0, stream>>>(in_deg, block_offs, row_ptr, N);
  group_offs_kernel<<<nBlocks, 256, 0, stream>>>(part_dst, row_ptr, goff, N);
  scatter_kernel<<<NB, 1024, 0, stream>>>(src, dst, ew, goff, csr, N, E, epb);

  // Layer 1: 256 -> 128, tanh. 64x64 tiles, 2 col-blocks -> 1024 blocks.
  gemm_transform<256, 128, 64, 64, 4, 4, 32><<<dim3(N / 64, 2), 256, 0, stream>>>(
      b_z, W1, norm_src, HT, N);
  aggregate_kernel<128><<<(N + 7) / 8, 256, 0, stream>>>(HT, row_ptr, csr, norm_dst, b1, ACT1, N);
  // Layer 2: 128 -> 64 (tanh) fused with layer-3 transform (64 -> 1)
  gemm_transform<128, 64, 64, 64, 4, 4, 32><<<dim3(N / 64, 1), 256, 0, stream>>>(
      ACT1, W2, norm_src, HT, N);
  aggregate2_fuse3<<<(N + 15) / 16, 256, 0, stream>>>(HT, row_ptr, csr, norm_dst, norm_src, b2,
                                                      W3, HT3, N);
  // Layer 3 aggregate: 1 col, no tanh
  aggregate3_kernel<<<nBlocks, 256, 0, stream>>>(HT3, row_ptr, csr, norm_dst, b3,
                                                 (float*)d_out, N);
}